// Round 2
// baseline (2631.576 us; speedup 1.0000x reference)
//
#include <hip/hip_runtime.h>
#include <math.h>

#define CH    8
#define NBINS 1024
#define WW    512

static const size_t PLANE = (size_t)NBINS * WW;   // 524288
static const size_t TENS  = 16 * PLANE;           // 8388608 (B*C planes)

// ---------------------------------------------------------------- frame norm
// LayerNorm over axis h (BINS) for each (b,c,w) column.
// grid = nbc*16 blocks (w-chunks of 32), 256 threads = (32 w, 8 h-groups)
__global__ __launch_bounds__(256)
void frame_norm_k(const float* __restrict__ X, const float* __restrict__ gw,
                  const float* __restrict__ gb, float* __restrict__ O,
                  int bc_base, int outLocal)
{
    int bcl = blockIdx.x >> 4, wt = blockIdx.x & 15;
    int bc = bc_base + bcl;
    const float* xb = X + (size_t)bc * PLANE + wt * 32;
    float* ob = O + (size_t)(outLocal ? bcl : bc) * PLANE + wt * 32;
    int wi = threadIdx.x & 31, hg = threadIdx.x >> 5;

    float s = 0.f, s2 = 0.f;
    for (int h = hg * 128; h < hg * 128 + 128; ++h) {
        float v = xb[(size_t)h * WW + wi];
        s += v; s2 += v * v;
    }
    __shared__ float sh[2][8][32];
    __shared__ float smean[32], srstd[32];
    sh[0][hg][wi] = s; sh[1][hg][wi] = s2;
    __syncthreads();
    if (threadIdx.x < 32) {
        float ts = 0.f, ts2 = 0.f;
        for (int g = 0; g < 8; ++g) { ts += sh[0][g][threadIdx.x]; ts2 += sh[1][g][threadIdx.x]; }
        float mean = ts * (1.f / 1024.f);
        float var  = ts2 * (1.f / 1024.f) - mean * mean;
        smean[threadIdx.x] = mean;
        srstd[threadIdx.x] = rsqrtf(var + 1e-5f);
    }
    __syncthreads();
    float mean = smean[wi], rstd = srstd[wi];
    for (int h = hg * 128; h < hg * 128 + 128; ++h) {
        float v = xb[(size_t)h * WW + wi];
        ob[(size_t)h * WW + wi] = (v - mean) * rstd * gw[h] + gb[h];
    }
}

// ---------------------------------------------------------------- conv 1x3
// y[b,o,h,w] = bias[o] + sum_{i,k} p[b,i,h,w+k-1] * W[o,i,0,k]
// grid = B*NBINS blocks, 256 threads. Safe to run IN-PLACE (P==O): each block
// stages all 8 input channels of its (b,h) row in LDS before any write.
__global__ __launch_bounds__(256)
void conv1x3_k(const float* __restrict__ P, const float* __restrict__ Wc,
               const float* __restrict__ Bc, float* __restrict__ O)
{
    int b = blockIdx.x >> 10, h = blockIdx.x & 1023;
    __shared__ float sp[CH][WW + 2];
    __shared__ float sw[CH * CH * 3];
    __shared__ float sb[CH];
    int tid = threadIdx.x;
    #pragma unroll
    for (int i = 0; i < CH; ++i) {
        size_t base = (((size_t)b * CH + i) * NBINS + h) * WW;
        sp[i][1 + tid]       = P[base + tid];
        sp[i][1 + 256 + tid] = P[base + 256 + tid];
    }
    if (tid < CH) { sp[tid][0] = 0.f; sp[tid][WW + 1] = 0.f; sb[tid] = Bc[tid]; }
    if (tid < CH * CH * 3) sw[tid] = Wc[tid];
    __syncthreads();
    #pragma unroll
    for (int o = 0; o < CH; ++o) {
        const float* wo = &sw[o * CH * 3];
        #pragma unroll
        for (int j = 0; j < 2; ++j) {
            int wx = tid + j * 256;
            float acc = sb[o];
            #pragma unroll
            for (int i = 0; i < CH; ++i)
                acc += sp[i][wx] * wo[i*3+0] + sp[i][wx+1] * wo[i*3+1] + sp[i][wx+2] * wo[i*3+2];
            O[(((size_t)b * CH + o) * NBINS + h) * WW + wx] = acc;
        }
    }
}

// ---------------------------------------------------------------- rotary
// Reads pc (global bc, h=n*256+d, w), writes qr layout (LOCAL bcn, w, d) with
// RoPE applied to d<128 (pairs), pass-through d>=128.
// grid = ga*16 (bcn-local x w-tiles of 32), 256 threads.
__global__ __launch_bounds__(256)
void rotary_k(const float* __restrict__ PC, float* __restrict__ QR, int bcn_base)
{
    int bcnl = blockIdx.x >> 4, wt = blockIdx.x & 15;
    int bcn = bcn_base + bcnl;
    int bc = bcn >> 2, n = bcn & 3;
    int w0 = wt * 32;
    __shared__ float tl[32][256 + 1];
    int tid = threadIdx.x;
    const float* src = PC + ((size_t)bc * NBINS + n * 256) * WW + w0;
    int wi = tid & 31, dbase = tid >> 5;      // 8 d-groups
    for (int rep = 0; rep < 32; ++rep) {
        int d = dbase * 32 + rep;
        tl[wi][d] = src[(size_t)d * WW + wi];
    }
    __syncthreads();
    int dp = tid & 127;       // pair index 0..127
    int wg = tid >> 7;        // 0..1
    bool rot = dp < 64;
    float freq = 0.f;
    if (rot) freq = exp2f(-0.20762050593048203f * (float)dp); // 10000^(-dp/64)
    for (int j = 0; j < 16; ++j) {
        int wl = wg * 16 + j;
        float t1 = tl[wl][2 * dp], t2 = tl[wl][2 * dp + 1];
        float o1, o2;
        if (rot) {
            float ang = (float)(w0 + wl) * freq;
            float sn, cn;
            sincosf(ang, &sn, &cn);
            o1 = t1 * cn - t2 * sn;
            o2 = t2 * cn + t1 * sn;
        } else { o1 = t1; o2 = t2; }
        float2* dst = (float2*)(QR + ((size_t)bcnl * WW + w0 + wl) * 256);
        dst[dp] = make_float2(o1, o2);
    }
}

// ---------------------------------------------------------------- softmax rows
// In-place row softmax, rows of 512. One wave per row.
__global__ __launch_bounds__(256)
void softmax_rows(float* __restrict__ S, int nrows)
{
    int gid = blockIdx.x * 256 + threadIdx.x;
    int row = gid >> 6, lane = threadIdx.x & 63;
    if (row >= nrows) return;
    float* r = S + (size_t)row * 512;
    float4 a = ((const float4*)r)[lane];
    float4 b = ((const float4*)r)[lane + 64];
    float mx = fmaxf(fmaxf(fmaxf(a.x, a.y), fmaxf(a.z, a.w)),
                     fmaxf(fmaxf(b.x, b.y), fmaxf(b.z, b.w)));
    for (int off = 32; off; off >>= 1) mx = fmaxf(mx, __shfl_xor(mx, off));
    a.x = __expf(a.x - mx); a.y = __expf(a.y - mx); a.z = __expf(a.z - mx); a.w = __expf(a.w - mx);
    b.x = __expf(b.x - mx); b.y = __expf(b.y - mx); b.z = __expf(b.z - mx); b.w = __expf(b.w - mx);
    float sm = a.x + a.y + a.z + a.w + b.x + b.y + b.z + b.w;
    for (int off = 32; off; off >>= 1) sm += __shfl_xor(sm, off);
    float inv = 1.f / sm;
    a.x *= inv; a.y *= inv; a.z *= inv; a.w *= inv;
    b.x *= inv; b.y *= inv; b.z *= inv; b.w *= inv;
    ((float4*)r)[lane] = a; ((float4*)r)[lane + 64] = b;
}

// ---------------------------------------------------------------- residual add
// O = A + B. Safe with O == B (read before write, same index).
__global__ __launch_bounds__(256)
void add_k(const float* __restrict__ A, const float* B,
           float* O, int n4)
{
    int i = blockIdx.x * 256 + threadIdx.x;
    if (i >= n4) return;
    float4 a = ((const float4*)A)[i];
    float4 b = ((const float4*)B)[i];
    ((float4*)O)[i] = make_float4(a.x + b.x, a.y + b.y, a.z + b.z, a.w + b.w);
}

// ---------------------------------------------------------------- GEMM NN
// C[o,w] = sum_h A[o,h] * X[h,w], per batch. Weight A indexed by channel
// c = (bc_base+lb)&7; X/C indexed local (lb) or global (bc).
// 128x128 tile, BK=8, 256 threads, 8x8 micro-tile.
// MODE: 0 = store, 1 = relu^2 store, 2 = add into C
template<int MODE>
__global__ __launch_bounds__(256)
void gemm_nn(const float* __restrict__ A, const float* __restrict__ X,
             float* __restrict__ C, int M, int N, int K,
             int tilesN, int tilesPerBatch, int bc_base,
             int xLocal, int cLocal)
{
    const int lb = blockIdx.x / tilesPerBatch;
    const int t  = blockIdx.x % tilesPerBatch;
    const int tm = t / tilesN, tn = t % tilesN;
    const int bc = bc_base + lb;
    const int c  = bc & 7;
    const float* Ab = A + (size_t)c * M * K;
    const float* Xb = X + (size_t)(xLocal ? lb : bc) * (size_t)K * N;
    float* Cb = C + (size_t)(cLocal ? lb : bc) * (size_t)M * N;

    __shared__ float As[8][128];
    __shared__ float Bs[8][128];

    const int tid  = threadIdx.x;
    const int arow = tid >> 1,  acol = (tid & 1) << 2;
    const int brow = tid >> 5,  bcol = (tid & 31) << 2;
    const int rg   = tid >> 4,  cg   = tid & 15;

    const float* ap = Ab + (size_t)(tm * 128 + arow) * K + acol;
    const float* xp = Xb + (size_t)brow * N + tn * 128 + bcol;

    float acc[8][8];
    #pragma unroll
    for (int i = 0; i < 8; ++i)
        #pragma unroll
        for (int j = 0; j < 8; ++j) acc[i][j] = 0.f;

    for (int k0 = 0; k0 < K; k0 += 8) {
        const float4 av = *(const float4*)(ap + k0);
        const float4 bv = *(const float4*)(xp + (size_t)k0 * N);
        __syncthreads();
        As[acol + 0][arow] = av.x;
        As[acol + 1][arow] = av.y;
        As[acol + 2][arow] = av.z;
        As[acol + 3][arow] = av.w;
        *(float4*)&Bs[brow][bcol] = bv;
        __syncthreads();
        #pragma unroll
        for (int kk = 0; kk < 8; ++kk) {
            float a0[8], b0[8];
            *(float4*)(&a0[0]) = *(const float4*)&As[kk][rg * 8];
            *(float4*)(&a0[4]) = *(const float4*)&As[kk][rg * 8 + 4];
            *(float4*)(&b0[0]) = *(const float4*)&Bs[kk][cg * 8];
            *(float4*)(&b0[4]) = *(const float4*)&Bs[kk][cg * 8 + 4];
            #pragma unroll
            for (int i = 0; i < 8; ++i)
                #pragma unroll
                for (int j = 0; j < 8; ++j)
                    acc[i][j] = fmaf(a0[i], b0[j], acc[i][j]);
        }
    }
    const int row0 = tm * 128 + rg * 8, col0 = tn * 128 + cg * 8;
    #pragma unroll
    for (int i = 0; i < 8; ++i) {
        float* cp = Cb + (size_t)(row0 + i) * N + col0;
        if (MODE == 0) {
            *(float4*)cp       = make_float4(acc[i][0], acc[i][1], acc[i][2], acc[i][3]);
            *(float4*)(cp + 4) = make_float4(acc[i][4], acc[i][5], acc[i][6], acc[i][7]);
        } else if (MODE == 1) {
            float r[8];
            #pragma unroll
            for (int j = 0; j < 8; ++j) { float v = fmaxf(acc[i][j], 0.f); r[j] = v * v; }
            *(float4*)cp       = make_float4(r[0], r[1], r[2], r[3]);
            *(float4*)(cp + 4) = make_float4(r[4], r[5], r[6], r[7]);
        } else {
            #pragma unroll
            for (int j = 0; j < 8; ++j) cp[j] += acc[i][j];
        }
    }
}

// ---------------------------------------------------------------- GEMM NT
// C[i,j] = scale * sum_k A[i,k] * B[j,k]; A (M,K), B (N,K) row-major.
// TRANS=1: write C transposed: Cb[j*ldt + i].
template<int TRANS>
__global__ __launch_bounds__(256)
void gemm_nt(const float* __restrict__ A, const float* __restrict__ Bm,
             float* __restrict__ C, int M, int N, int K,
             int tilesN, int tilesPerBatch,
             size_t aStride, size_t bStride, size_t cStride,
             int ldt, float scale)
{
    const int batch = blockIdx.x / tilesPerBatch;
    const int t  = blockIdx.x % tilesPerBatch;
    const int tm = t / tilesN, tn = t % tilesN;
    const float* Ab = A  + (size_t)batch * aStride;
    const float* Bb = Bm + (size_t)batch * bStride;
    float* Cb = C + (size_t)batch * cStride;

    __shared__ float As[8][128];
    __shared__ float Bs[8][128];

    const int tid  = threadIdx.x;
    const int arow = tid >> 1, acol = (tid & 1) << 2;
    const int rg   = tid >> 4, cg   = tid & 15;

    const float* ap = Ab + (size_t)(tm * 128 + arow) * K + acol;
    const float* bp = Bb + (size_t)(tn * 128 + arow) * K + acol;

    float acc[8][8];
    #pragma unroll
    for (int i = 0; i < 8; ++i)
        #pragma unroll
        for (int j = 0; j < 8; ++j) acc[i][j] = 0.f;

    for (int k0 = 0; k0 < K; k0 += 8) {
        const float4 av = *(const float4*)(ap + k0);
        const float4 bv = *(const float4*)(bp + k0);
        __syncthreads();
        As[acol + 0][arow] = av.x;
        As[acol + 1][arow] = av.y;
        As[acol + 2][arow] = av.z;
        As[acol + 3][arow] = av.w;
        Bs[acol + 0][arow] = bv.x;
        Bs[acol + 1][arow] = bv.y;
        Bs[acol + 2][arow] = bv.z;
        Bs[acol + 3][arow] = bv.w;
        __syncthreads();
        #pragma unroll
        for (int kk = 0; kk < 8; ++kk) {
            float a0[8], b0[8];
            *(float4*)(&a0[0]) = *(const float4*)&As[kk][rg * 8];
            *(float4*)(&a0[4]) = *(const float4*)&As[kk][rg * 8 + 4];
            *(float4*)(&b0[0]) = *(const float4*)&Bs[kk][cg * 8];
            *(float4*)(&b0[4]) = *(const float4*)&Bs[kk][cg * 8 + 4];
            #pragma unroll
            for (int i = 0; i < 8; ++i)
                #pragma unroll
                for (int j = 0; j < 8; ++j)
                    acc[i][j] = fmaf(a0[i], b0[j], acc[i][j]);
        }
    }
    const int row0 = tm * 128 + rg * 8, col0 = tn * 128 + cg * 8;
    if (!TRANS) {
        #pragma unroll
        for (int i = 0; i < 8; ++i) {
            float* cp = Cb + (size_t)(row0 + i) * N + col0;
            *(float4*)cp       = make_float4(acc[i][0]*scale, acc[i][1]*scale, acc[i][2]*scale, acc[i][3]*scale);
            *(float4*)(cp + 4) = make_float4(acc[i][4]*scale, acc[i][5]*scale, acc[i][6]*scale, acc[i][7]*scale);
        }
    } else {
        #pragma unroll
        for (int j = 0; j < 8; ++j) {
            float* cp = Cb + (size_t)(col0 + j) * ldt + row0;
            *(float4*)cp       = make_float4(acc[0][j]*scale, acc[1][j]*scale, acc[2][j]*scale, acc[3][j]*scale);
            *(float4*)(cp + 4) = make_float4(acc[4][j]*scale, acc[5][j]*scale, acc[6][j]*scale, acc[7][j]*scale);
        }
    }
}

// ---------------------------------------------------------------- launcher
// Workspace budget is adaptive: peak use = max(TENS floats for z1,
// ga*(qr+scores) floats, gm*(z+hidden) floats). Needs ws_size >= 33.5 MB.
extern "C" void kernel_launch(void* const* d_in, const int* in_sizes, int n_in,
                              void* d_out, int out_size, void* d_ws, size_t ws_size,
                              hipStream_t stream)
{
    const float* x        = (const float*)d_in[0];
    const float* ln1_w    = (const float*)d_in[1];
    const float* ln1_b    = (const float*)d_in[2];
    const float* q_mcl_w  = (const float*)d_in[3];
    const float* q_conv_w = (const float*)d_in[4];
    const float* q_conv_b = (const float*)d_in[5];
    const float* out_mcl_w= (const float*)d_in[6];
    const float* ln2_w    = (const float*)d_in[7];
    const float* ln2_b    = (const float*)d_in[8];
    const float* lin1_w   = (const float*)d_in[9];
    const float* lin2_w   = (const float*)d_in[10];
    float* OUT = (float*)d_out;
    float* W   = (float*)d_ws;
    const size_t wsf = ws_size / 4;   // floats available

    // choose attention group size (bcn per group; multiple of 4, divisor of 64)
    int ga = 4;
    {   const int cands[5] = {64, 32, 16, 8, 4};
        for (int i = 0; i < 5; ++i)
            if ((size_t)cands[i] * (131072 + 262144) <= wsf) { ga = cands[i]; break; }
    }
    // choose MLP group size (bc per group; divisor of 16)
    int gm = 1;
    {   const int cands[5] = {16, 8, 4, 2, 1};
        for (int i = 0; i < 5; ++i)
            if ((size_t)cands[i] * (524288 + 2097152) <= wsf) { gm = cands[i]; break; }
    }

    // 1. z1 = frame_norm(x) -> W (full tensor)
    frame_norm_k<<<256, 256, 0, stream>>>(x, ln1_w, ln1_b, W, 0, 0);
    // 2. p = mcl(z1, q_mcl_w) -> OUT  (M=1024,N=512,K=1024, per bc)
    gemm_nn<0><<<16 * 32, 256, 0, stream>>>(q_mcl_w, W, OUT, 1024, 512, 1024,
                                            4, 32, 0, 0, 0);
    // 3. pc = conv1x3(p), in place on OUT
    conv1x3_k<<<2048, 256, 0, stream>>>(OUT, q_conv_w, q_conv_b, OUT);

    // 4. attention, chunked over groups of ga bcn batches
    {
        float* Wq = W;                              // ga * 131072 floats (qr, then att)
        float* Ws = W + (size_t)ga * 131072;        // ga * 262144 floats (scores)
        const int nG = 64 / ga;
        for (int g = 0; g < nG; ++g) {
            const int bcn0 = g * ga;
            // 4a. qr = rotary(pc[group]) -> Wq (local)
            rotary_k<<<ga * 16, 256, 0, stream>>>(OUT, Wq, bcn0);
            // 4b. scores = qr @ qr^T / 32 -> Ws
            gemm_nt<0><<<ga * 16, 256, 0, stream>>>(Wq, Wq, Ws, 512, 512, 256,
                4, 16, (size_t)131072, (size_t)131072, (size_t)262144, 0, 0.03125f);
            // 4c. softmax rows
            softmax_rows<<<ga * 128, 256, 0, stream>>>(Ws, ga * 512);
            // 4d. att = P @ V -> Wq (overwrites dead qr; transposed to (d,w))
            gemm_nt<1><<<ga * 8, 256, 0, stream>>>(Ws, OUT + (size_t)bcn0 * 131072, Wq,
                512, 256, 512, 2, 8, (size_t)262144, (size_t)131072, (size_t)131072,
                512, 1.0f);
            // 4e. z_att = mcl(att, out_mcl_w) -> OUT planes of this group
            //     (overwrites pc planes of this group, which are now dead)
            gemm_nn<0><<<(ga / 4) * 32, 256, 0, stream>>>(out_mcl_w, Wq, OUT,
                1024, 512, 1024, 4, 32, bcn0 / 4, 1, 0);
        }
    }

    // 5. x1 = x + z_att, in place on OUT
    add_k<<<8192, 256, 0, stream>>>(x, OUT, OUT, (int)(TENS / 4));

    // 6. MLP, chunked over groups of gm channels
    {
        float* Wz = W;                              // gm * PLANE floats (z2)
        float* Wh = W + (size_t)gm * PLANE;         // gm * 2097152 floats (hidden)
        const int nG = 16 / gm;
        for (int g = 0; g < nG; ++g) {
            const int bc0 = g * gm;
            // 6a. z2 = frame_norm(x1[group]) -> Wz (local planes)
            frame_norm_k<<<gm * 16, 256, 0, stream>>>(OUT, ln2_w, ln2_b, Wz, bc0, 1);
            // 6b. hidden = relu(lin1 @ z2)^2 -> Wh (local)
            gemm_nn<1><<<gm * 128, 256, 0, stream>>>(lin1_w, Wz, Wh, 4096, 512, 1024,
                                                     4, 128, bc0, 1, 1);
            // 6c. OUT += lin2 @ hidden
            gemm_nn<2><<<gm * 32, 256, 0, stream>>>(lin2_w, Wh, OUT, 1024, 512, 4096,
                                                    4, 32, bc0, 1, 0);
        }
    }
}

// Round 3
// 747.394 us; speedup vs baseline: 3.5210x; 3.5210x over previous
//
#include <hip/hip_runtime.h>
#include <math.h>

typedef unsigned short u16;
#define CH    8
#define NBINS 1024
#define WW    512

static const size_t PLANE = (size_t)NBINS * WW;   // 524288
static const size_t TENS  = 16 * PLANE;           // 8388608

using bf16x8 = __attribute__((ext_vector_type(8))) short;
using f32x4  = __attribute__((ext_vector_type(4))) float;

__device__ __forceinline__ u16 bfr(float f) {
    union { float f; unsigned u; } x; x.f = f;
    return (u16)((x.u + 0x7FFFu + ((x.u >> 16) & 1u)) >> 16);
}

// ---------------------------------------------------------------- fp32 -> bf16
__global__ __launch_bounds__(256)
void cvt_k(const float* __restrict__ src, u16* __restrict__ dst, int n4)
{
    int i = blockIdx.x * 256 + threadIdx.x;
    if (i >= n4) return;
    float4 f = ((const float4*)src)[i];
    ushort4 o;
    o.x = bfr(f.x); o.y = bfr(f.y); o.z = bfr(f.z); o.w = bfr(f.w);
    ((ushort4*)dst)[i] = o;
}

// ---------------------------------------------------------------- frame norm -> transposed bf16
// LayerNorm over h (1024) per (bc,w) column; writes O[lb][w][h] bf16.
// grid = nbc*16 (w-chunks of 32), 256 thr = (32 w, 8 h-groups)
__global__ __launch_bounds__(256)
void frame_norm_t(const float* __restrict__ X, const float* __restrict__ gw,
                  const float* __restrict__ gb, u16* __restrict__ O,
                  int useMap, int mc, int cBase)
{
    int lb = blockIdx.x >> 4, wt = blockIdx.x & 15;
    int bc = useMap ? ((lb / mc) * 8 + cBase + (lb % mc)) : lb;
    const float* xb = X + (size_t)bc * PLANE + wt * 32;
    int wi = threadIdx.x & 31, hg = threadIdx.x >> 5;

    float s = 0.f, s2 = 0.f;
    for (int h = hg * 128; h < hg * 128 + 128; ++h) {
        float v = xb[(size_t)h * WW + wi];
        s += v; s2 += v * v;
    }
    __shared__ float sh[2][8][32];
    __shared__ float smean[32], srstd[32];
    sh[0][hg][wi] = s; sh[1][hg][wi] = s2;
    __syncthreads();
    if (threadIdx.x < 32) {
        float ts = 0.f, ts2 = 0.f;
        for (int g = 0; g < 8; ++g) { ts += sh[0][g][threadIdx.x]; ts2 += sh[1][g][threadIdx.x]; }
        float mean = ts * (1.f / 1024.f);
        float var  = ts2 * (1.f / 1024.f) - mean * mean;
        smean[threadIdx.x] = mean;
        srstd[threadIdx.x] = rsqrtf(var + 1e-5f);
    }
    __syncthreads();
    float mean = smean[wi], rstd = srstd[wi];
    u16* ob = O + ((size_t)lb * 512 + wt * 32 + wi) * 1024;
    for (int h0 = hg * 128; h0 < hg * 128 + 128; h0 += 4) {
        ushort4 pk;
        float v0 = xb[(size_t)(h0+0) * WW + wi];
        float v1 = xb[(size_t)(h0+1) * WW + wi];
        float v2 = xb[(size_t)(h0+2) * WW + wi];
        float v3 = xb[(size_t)(h0+3) * WW + wi];
        pk.x = bfr((v0 - mean) * rstd * gw[h0+0] + gb[h0+0]);
        pk.y = bfr((v1 - mean) * rstd * gw[h0+1] + gb[h0+1]);
        pk.z = bfr((v2 - mean) * rstd * gw[h0+2] + gb[h0+2]);
        pk.w = bfr((v3 - mean) * rstd * gw[h0+3] + gb[h0+3]);
        *(ushort4*)&ob[h0] = pk;
    }
}

// ---------------------------------------------------------------- conv 1x3 (fp32, in-place safe)
__global__ __launch_bounds__(256)
void conv1x3_k(const float* __restrict__ P, const float* __restrict__ Wc,
               const float* __restrict__ Bc, float* __restrict__ O)
{
    int b = blockIdx.x >> 10, h = blockIdx.x & 1023;
    __shared__ float sp[CH][WW + 2];
    __shared__ float sw[CH * CH * 3];
    __shared__ float sb[CH];
    int tid = threadIdx.x;
    #pragma unroll
    for (int i = 0; i < CH; ++i) {
        size_t base = (((size_t)b * CH + i) * NBINS + h) * WW;
        sp[i][1 + tid]       = P[base + tid];
        sp[i][1 + 256 + tid] = P[base + 256 + tid];
    }
    if (tid < CH) { sp[tid][0] = 0.f; sp[tid][WW + 1] = 0.f; sb[tid] = Bc[tid]; }
    if (tid < CH * CH * 3) sw[tid] = Wc[tid];
    __syncthreads();
    #pragma unroll
    for (int o = 0; o < CH; ++o) {
        const float* wo = &sw[o * CH * 3];
        #pragma unroll
        for (int j = 0; j < 2; ++j) {
            int wx = tid + j * 256;
            float acc = sb[o];
            #pragma unroll
            for (int i = 0; i < CH; ++i)
                acc += sp[i][wx] * wo[i*3+0] + sp[i][wx+1] * wo[i*3+1] + sp[i][wx+2] * wo[i*3+2];
            O[(((size_t)b * CH + o) * NBINS + h) * WW + wx] = acc;
        }
    }
}

// ---------------------------------------------------------------- rotary -> QR bf16 (w,d) + VT bf16 (d,w)
// grid = ga*16, 256 thr.
__global__ __launch_bounds__(256)
void rotary_qv(const float* __restrict__ PC, u16* __restrict__ QR,
               u16* __restrict__ VT, int bcn_base)
{
    int bcnl = blockIdx.x >> 4, wt = blockIdx.x & 15;
    int bcn = bcn_base + bcnl;
    int bc = bcn >> 2, n = bcn & 3;
    int w0 = wt * 32;
    __shared__ float tl[32][256 + 1];
    int tid = threadIdx.x;
    const float* src = PC + ((size_t)bc * NBINS + n * 256) * WW + w0;
    int wi = tid & 31, dbase = tid >> 5;
    for (int rep = 0; rep < 32; ++rep) {
        int d = dbase * 32 + rep;
        float v = src[(size_t)d * WW + wi];
        tl[wi][d] = v;
        VT[((size_t)bcnl * 256 + d) * 512 + w0 + wi] = bfr(v);
    }
    __syncthreads();
    int dp = tid & 127;
    int wg = tid >> 7;
    bool rot = dp < 64;
    float freq = 0.f;
    if (rot) freq = exp2f(-0.20762050593048203f * (float)dp); // 10000^(-dp/64)
    for (int j = 0; j < 16; ++j) {
        int wl = wg * 16 + j;
        float t1 = tl[wl][2 * dp], t2 = tl[wl][2 * dp + 1];
        float o1, o2;
        if (rot) {
            float ang = (float)(w0 + wl) * freq;
            float sn, cn;
            sincosf(ang, &sn, &cn);
            o1 = t1 * cn - t2 * sn;
            o2 = t2 * cn + t1 * sn;
        } else { o1 = t1; o2 = t2; }
        ushort2 pk; pk.x = bfr(o1); pk.y = bfr(o2);
        *(ushort2*)&QR[((size_t)bcnl * 512 + w0 + wl) * 256 + 2 * dp] = pk;
    }
}

// ---------------------------------------------------------------- softmax fp32 rows -> bf16 P
__global__ __launch_bounds__(256)
void softmax_bf(const float* __restrict__ S, u16* __restrict__ P, int nrows)
{
    int gid = blockIdx.x * 256 + threadIdx.x;
    int row = gid >> 6, lane = threadIdx.x & 63;
    if (row >= nrows) return;
    const float* r = S + (size_t)row * 512;
    float4 a = ((const float4*)r)[lane];
    float4 b = ((const float4*)r)[lane + 64];
    float mx = fmaxf(fmaxf(fmaxf(a.x, a.y), fmaxf(a.z, a.w)),
                     fmaxf(fmaxf(b.x, b.y), fmaxf(b.z, b.w)));
    for (int off = 32; off; off >>= 1) mx = fmaxf(mx, __shfl_xor(mx, off));
    a.x = __expf(a.x - mx); a.y = __expf(a.y - mx); a.z = __expf(a.z - mx); a.w = __expf(a.w - mx);
    b.x = __expf(b.x - mx); b.y = __expf(b.y - mx); b.z = __expf(b.z - mx); b.w = __expf(b.w - mx);
    float sm = a.x + a.y + a.z + a.w + b.x + b.y + b.z + b.w;
    for (int off = 32; off; off >>= 1) sm += __shfl_xor(sm, off);
    float inv = 1.f / sm;
    u16* pr = P + (size_t)row * 512;
    ushort4 pa, pb;
    pa.x = bfr(a.x*inv); pa.y = bfr(a.y*inv); pa.z = bfr(a.z*inv); pa.w = bfr(a.w*inv);
    pb.x = bfr(b.x*inv); pb.y = bfr(b.y*inv); pb.z = bfr(b.z*inv); pb.w = bfr(b.w*inv);
    *(ushort4*)&pr[4 * lane]       = pa;
    *(ushort4*)&pr[256 + 4 * lane] = pb;
}

// ---------------------------------------------------------------- residual add
__global__ __launch_bounds__(256)
void add_k(const float* __restrict__ A, const float* B, float* O, int n4)
{
    int i = blockIdx.x * 256 + threadIdx.x;
    if (i >= n4) return;
    float4 a = ((const float4*)A)[i];
    float4 b = ((const float4*)B)[i];
    ((float4*)O)[i] = make_float4(a.x + b.x, a.y + b.y, a.z + b.z, a.w + b.w);
}

// ---------------------------------------------------------------- bf16 MFMA GEMM (NT)
// C[m,n] = sum_k A[m,k]*B[n,k], A (M,K) B (N,K) bf16 row-major.
// 128x128 tile, BK=64, 4 waves (2x2), global_load_lds + XOR-swizzled LDS.
// MODE 0: C fp32 = acc*scale; 1: C bf16 = acc; 2: CT bf16 = relu(acc)^2 (transposed, ldC = M);
// MODE 3: C fp32 += acc.
// aIdx = (batch+aAdd)%aMod; bIdx = batch;
// cOff = cMul1*(batch/cDiv) + cMul2*(batch%cDiv) + cAdd2  (elements).
template<int MODE>
__global__ __launch_bounds__(256)
void gemm_bt(const u16* __restrict__ A, const u16* __restrict__ B,
             void* __restrict__ Cvoid,
             int K, int tilesN, int tilesPerBatch,
             size_t aStride, size_t bStride,
             int aAdd, int aMod,
             int cDiv, size_t cMul1, size_t cMul2, size_t cAdd2,
             int ldC, float scale)
{
    const int batch = blockIdx.x / tilesPerBatch;
    const int t  = blockIdx.x % tilesPerBatch;
    const int tm = t / tilesN, tn = t % tilesN;
    const int aIdx = (batch + aAdd) % aMod;
    const size_t cOff = cMul1 * (size_t)(batch / cDiv) + cMul2 * (size_t)(batch % cDiv) + cAdd2;

    const u16* Ab = A + (size_t)aIdx * aStride + (size_t)(tm * 128) * K;
    const u16* Bb = B + (size_t)batch * bStride + (size_t)(tn * 128) * K;

    __shared__ u16 As[128 * 64];
    __shared__ u16 Bs[128 * 64];

    const int tid = threadIdx.x;
    const int wv = tid >> 6, l = tid & 63;
    const int wm = wv >> 1, wn = wv & 1;
    const int lr = l & 15, lk = l >> 4;

    f32x4 acc[4][4];
    #pragma unroll
    for (int i = 0; i < 4; ++i)
        #pragma unroll
        for (int j = 0; j < 4; ++j)
            acc[i][j] = (f32x4){0.f, 0.f, 0.f, 0.f};

    for (int k0 = 0; k0 < K; k0 += 64) {
        __syncthreads();            // prior reads done before LDS overwrite
        #pragma unroll
        for (int it = 0; it < 4; ++it) {
            int chunk = (it * 4 + wv) * 64 + l;     // 0..1023 (16B chunks)
            int row = chunk >> 3, cb = chunk & 7;
            int cbg = cb ^ (row & 7);               // inverse-swizzled source chunk
            const char* sa = (const char*)Ab + ((size_t)row * K + k0 + cbg * 8) * 2;
            const char* sb = (const char*)Bb + ((size_t)row * K + k0 + cbg * 8) * 2;
            char* da = (char*)As + (it * 4 + wv) * 1024;
            char* db = (char*)Bs + (it * 4 + wv) * 1024;
            __builtin_amdgcn_global_load_lds((const __attribute__((address_space(1))) void*)sa,
                                             (__attribute__((address_space(3))) void*)da, 16, 0, 0);
            __builtin_amdgcn_global_load_lds((const __attribute__((address_space(1))) void*)sb,
                                             (__attribute__((address_space(3))) void*)db, 16, 0, 0);
        }
        __syncthreads();            // implies vmcnt(0): staging visible to all
        #pragma unroll
        for (int kk = 0; kk < 2; ++kk) {
            bf16x8 av[4], bv[4];
            #pragma unroll
            for (int mi = 0; mi < 4; ++mi) {
                int row = wm * 64 + mi * 16 + lr;
                int off = row * 128 + (((kk << 6) | (lk << 4)) ^ ((row & 7) << 4));
                av[mi] = *(const bf16x8*)((const char*)As + off);
            }
            #pragma unroll
            for (int ni = 0; ni < 4; ++ni) {
                int row = wn * 64 + ni * 16 + lr;
                int off = row * 128 + (((kk << 6) | (lk << 4)) ^ ((row & 7) << 4));
                bv[ni] = *(const bf16x8*)((const char*)Bs + off);
            }
            #pragma unroll
            for (int mi = 0; mi < 4; ++mi)
                #pragma unroll
                for (int ni = 0; ni < 4; ++ni)
                    acc[mi][ni] = __builtin_amdgcn_mfma_f32_16x16x32_bf16(
                        av[mi], bv[ni], acc[mi][ni], 0, 0, 0);
        }
    }

    const int rowBase = tm * 128 + wm * 64;
    const int colBase = tn * 128 + wn * 64;
    if (MODE == 0) {
        float* Cf = (float*)Cvoid;
        #pragma unroll
        for (int mi = 0; mi < 4; ++mi)
            #pragma unroll
            for (int ni = 0; ni < 4; ++ni) {
                int r0 = rowBase + mi * 16 + lk * 4;
                int c  = colBase + ni * 16 + lr;
                #pragma unroll
                for (int r = 0; r < 4; ++r)
                    Cf[cOff + (size_t)(r0 + r) * ldC + c] = acc[mi][ni][r] * scale;
            }
    } else if (MODE == 1) {
        u16* Cb = (u16*)Cvoid;
        #pragma unroll
        for (int mi = 0; mi < 4; ++mi)
            #pragma unroll
            for (int ni = 0; ni < 4; ++ni) {
                int r0 = rowBase + mi * 16 + lk * 4;
                int c  = colBase + ni * 16 + lr;
                #pragma unroll
                for (int r = 0; r < 4; ++r)
                    Cb[cOff + (size_t)(r0 + r) * ldC + c] = bfr(acc[mi][ni][r]);
            }
    } else if (MODE == 2) {
        u16* Cb = (u16*)Cvoid;
        #pragma unroll
        for (int mi = 0; mi < 4; ++mi)
            #pragma unroll
            for (int ni = 0; ni < 4; ++ni) {
                int r0 = rowBase + mi * 16 + lk * 4;
                int c  = colBase + ni * 16 + lr;
                ushort4 pk;
                float v0 = fmaxf(acc[mi][ni][0], 0.f);
                float v1 = fmaxf(acc[mi][ni][1], 0.f);
                float v2 = fmaxf(acc[mi][ni][2], 0.f);
                float v3 = fmaxf(acc[mi][ni][3], 0.f);
                pk.x = bfr(v0 * v0); pk.y = bfr(v1 * v1);
                pk.z = bfr(v2 * v2); pk.w = bfr(v3 * v3);
                *(ushort4*)&Cb[cOff + (size_t)c * ldC + r0] = pk;
            }
    } else {
        float* Cf = (float*)Cvoid;
        #pragma unroll
        for (int mi = 0; mi < 4; ++mi)
            #pragma unroll
            for (int ni = 0; ni < 4; ++ni) {
                int r0 = rowBase + mi * 16 + lk * 4;
                int c  = colBase + ni * 16 + lr;
                #pragma unroll
                for (int r = 0; r < 4; ++r)
                    Cf[cOff + (size_t)(r0 + r) * ldC + c] += acc[mi][ni][r];
            }
    }
}

// ---------------------------------------------------------------- launcher
extern "C" void kernel_launch(void* const* d_in, const int* in_sizes, int n_in,
                              void* d_out, int out_size, void* d_ws, size_t ws_size,
                              hipStream_t stream)
{
    const float* x        = (const float*)d_in[0];
    const float* ln1_w    = (const float*)d_in[1];
    const float* ln1_b    = (const float*)d_in[2];
    const float* q_mcl_w  = (const float*)d_in[3];
    const float* q_conv_w = (const float*)d_in[4];
    const float* q_conv_b = (const float*)d_in[5];
    const float* out_mcl_w= (const float*)d_in[6];
    const float* ln2_w    = (const float*)d_in[7];
    const float* ln2_b    = (const float*)d_in[8];
    const float* lin1_w   = (const float*)d_in[9];
    const float* lin2_w   = (const float*)d_in[10];
    float* OUT = (float*)d_out;
    char*  WB  = (char*)d_ws;

    // adaptive group sizes (bytes): phase B needs 16.8MB + ga*2.25MB;
    // phase C needs mc*18MB.
    int ga = 4;
    {   const int cands[4] = {32, 16, 8, 4};
        for (int i = 0; i < 4; ++i)
            if (16777216ull + (size_t)cands[i] * 2359296ull <= ws_size) { ga = cands[i]; break; }
    }
    int mc = 1;
    {   const int cands[3] = {4, 2, 1};
        for (int i = 0; i < 3; ++i)
            if ((size_t)cands[i] * 18874368ull <= ws_size) { mc = cands[i]; break; }
    }

    // ---- Phase A: norm1 + q_mcl + conv
    u16* QW  = (u16*)WB;                    // 16.8MB
    u16* Z1T = (u16*)(WB + 16777216);       // 16.8MB
    cvt_k<<<8192, 256, 0, stream>>>(q_mcl_w, QW, 2097152);
    frame_norm_t<<<256, 256, 0, stream>>>(x, ln1_w, ln1_b, Z1T, 0, 1, 0);
    gemm_bt<0><<<512, 256, 0, stream>>>(QW, Z1T, OUT, 1024, 4, 32,
        1048576, 524288, 0, 8, 1, PLANE, 0, 0, 512, 1.f);
    conv1x3_k<<<2048, 256, 0, stream>>>(OUT, q_conv_w, q_conv_b, OUT);

    // ---- Phase B: attention, groups of ga bcn
    u16* OW = (u16*)WB;                                         // 16.8MB (reuse QW)
    char* pb = WB + 16777216;
    u16*   QR = (u16*)pb;                                       // ga*256KB
    u16*   VT = (u16*)(pb + (size_t)ga * 262144);               // ga*256KB
    float* S  = (float*)(pb + (size_t)ga * 524288);             // ga*1MB
    u16*   P  = (u16*)(pb + (size_t)ga * 1572864);              // ga*512KB
    u16*   A2 = (u16*)(pb + (size_t)ga * 2097152);              // (ga/4)*1MB
    cvt_k<<<8192, 256, 0, stream>>>(out_mcl_w, OW, 2097152);
    {
        const int nG = 64 / ga;
        for (int g = 0; g < nG; ++g) {
            const int bcn0 = g * ga, bc0 = bcn0 / 4;
            rotary_qv<<<ga * 16, 256, 0, stream>>>(OUT, QR, VT, bcn0);
            gemm_bt<0><<<ga * 16, 256, 0, stream>>>(QR, QR, S, 256, 4, 16,
                131072, 131072, 0, 1000000, 1, 262144, 0, 0, 512, 0.03125f);
            softmax_bf<<<ga * 128, 256, 0, stream>>>(S, P, ga * 512);
            gemm_bt<1><<<ga * 8, 256, 0, stream>>>(P, VT, A2, 512, 2, 8,
                262144, 131072, 0, 1000000, 4, 524288, 256, 0, 1024, 1.f);
            gemm_bt<0><<<(ga / 4) * 32, 256, 0, stream>>>(OW, A2, OUT, 1024, 4, 32,
                1048576, 524288, bc0, 8, 1, PLANE, 0, (size_t)bc0 * PLANE, 512, 1.f);
        }
    }

    // ---- residual
    add_k<<<8192, 256, 0, stream>>>(x, OUT, OUT, (int)(TENS / 4));

    // ---- Phase C: MLP, groups of mc channels (both batches => 2mc local)
    u16* WC  = (u16*)WB;                                        // mc*8.4MB
    u16* Z2T = (u16*)(WB + (size_t)mc * 8388608);               // 2mc*1MB
    u16* HT  = (u16*)(WB + (size_t)mc * 8388608 + (size_t)mc * 2097152); // 2mc*4.2MB
    {
        const int nG = 8 / mc;
        for (int g = 0; g < nG; ++g) {
            const int cBase = g * mc;
            cvt_k<<<mc * 4096, 256, 0, stream>>>(lin1_w + (size_t)cBase * 4194304, WC, mc * 1048576);
            frame_norm_t<<<2 * mc * 16, 256, 0, stream>>>(OUT, ln2_w, ln2_b, Z2T, 1, mc, cBase);
            gemm_bt<2><<<2 * mc * 128, 256, 0, stream>>>(WC, Z2T, HT, 1024, 4, 128,
                4194304, 524288, 0, mc, 1, 2097152, 0, 0, 4096, 1.f);
            cvt_k<<<mc * 4096, 256, 0, stream>>>(lin2_w + (size_t)cBase * 4194304, WC, mc * 1048576);
            gemm_bt<3><<<2 * mc * 32, 256, 0, stream>>>(WC, HT, OUT, 4096, 4, 32,
                4194304, 2097152, 0, mc, mc, 8 * PLANE, PLANE, (size_t)cBase * PLANE, 512, 1.f);
        }
    }
}

// Round 4
// 659.242 us; speedup vs baseline: 3.9918x; 1.1337x over previous
//
#include <hip/hip_runtime.h>
#include <math.h>

typedef unsigned short u16;
#define CH    8
#define NBINS 1024
#define WW    512

static const size_t PLANE = (size_t)NBINS * WW;   // 524288
static const size_t TENS  = 16 * PLANE;           // 8388608

using bf16x8 = __attribute__((ext_vector_type(8))) short;
using f32x4  = __attribute__((ext_vector_type(4))) float;

__device__ __forceinline__ u16 bfr(float f) {
    union { float f; unsigned u; } x; x.f = f;
    return (u16)((x.u + 0x7FFFu + ((x.u >> 16) & 1u)) >> 16);
}

// ---------------------------------------------------------------- fp32 -> bf16
__global__ __launch_bounds__(256)
void cvt_k(const float* __restrict__ src, u16* __restrict__ dst, int n4)
{
    int i = blockIdx.x * 256 + threadIdx.x;
    if (i >= n4) return;
    float4 f = ((const float4*)src)[i];
    ushort4 o;
    o.x = bfr(f.x); o.y = bfr(f.y); o.z = bfr(f.z); o.w = bfr(f.w);
    ((ushort4*)dst)[i] = o;
}

// ---------------------------------------------------------------- frame norm -> transposed bf16
// LayerNorm over h (1024) per (bc,w) column; writes O[lb][w][h] bf16.
__global__ __launch_bounds__(256)
void frame_norm_t(const float* __restrict__ X, const float* __restrict__ gw,
                  const float* __restrict__ gb, u16* __restrict__ O,
                  int useMap, int mc, int cBase)
{
    int lb = blockIdx.x >> 4, wt = blockIdx.x & 15;
    int bc = useMap ? ((lb / mc) * 8 + cBase + (lb % mc)) : lb;
    const float* xb = X + (size_t)bc * PLANE + wt * 32;
    int wi = threadIdx.x & 31, hg = threadIdx.x >> 5;

    float s = 0.f, s2 = 0.f;
    for (int h = hg * 128; h < hg * 128 + 128; ++h) {
        float v = xb[(size_t)h * WW + wi];
        s += v; s2 += v * v;
    }
    __shared__ float sh[2][8][32];
    __shared__ float smean[32], srstd[32];
    sh[0][hg][wi] = s; sh[1][hg][wi] = s2;
    __syncthreads();
    if (threadIdx.x < 32) {
        float ts = 0.f, ts2 = 0.f;
        for (int g = 0; g < 8; ++g) { ts += sh[0][g][threadIdx.x]; ts2 += sh[1][g][threadIdx.x]; }
        float mean = ts * (1.f / 1024.f);
        float var  = ts2 * (1.f / 1024.f) - mean * mean;
        smean[threadIdx.x] = mean;
        srstd[threadIdx.x] = rsqrtf(var + 1e-5f);
    }
    __syncthreads();
    float mean = smean[wi], rstd = srstd[wi];
    u16* ob = O + ((size_t)lb * 512 + wt * 32 + wi) * 1024;
    for (int h0 = hg * 128; h0 < hg * 128 + 128; h0 += 4) {
        ushort4 pk;
        float v0 = xb[(size_t)(h0+0) * WW + wi];
        float v1 = xb[(size_t)(h0+1) * WW + wi];
        float v2 = xb[(size_t)(h0+2) * WW + wi];
        float v3 = xb[(size_t)(h0+3) * WW + wi];
        pk.x = bfr((v0 - mean) * rstd * gw[h0+0] + gb[h0+0]);
        pk.y = bfr((v1 - mean) * rstd * gw[h0+1] + gb[h0+1]);
        pk.z = bfr((v2 - mean) * rstd * gw[h0+2] + gb[h0+2]);
        pk.w = bfr((v3 - mean) * rstd * gw[h0+3] + gb[h0+3]);
        *(ushort4*)&ob[h0] = pk;
    }
}

// ---------------------------------------------------------------- conv 1x3 (fp32, in-place safe)
__global__ __launch_bounds__(256)
void conv1x3_k(const float* __restrict__ P, const float* __restrict__ Wc,
               const float* __restrict__ Bc, float* __restrict__ O)
{
    int b = blockIdx.x >> 10, h = blockIdx.x & 1023;
    __shared__ float sp[CH][WW + 2];
    __shared__ float sw[CH * CH * 3];
    __shared__ float sb[CH];
    int tid = threadIdx.x;
    #pragma unroll
    for (int i = 0; i < CH; ++i) {
        size_t base = (((size_t)b * CH + i) * NBINS + h) * WW;
        sp[i][1 + tid]       = P[base + tid];
        sp[i][1 + 256 + tid] = P[base + 256 + tid];
    }
    if (tid < CH) { sp[tid][0] = 0.f; sp[tid][WW + 1] = 0.f; sb[tid] = Bc[tid]; }
    if (tid < CH * CH * 3) sw[tid] = Wc[tid];
    __syncthreads();
    #pragma unroll
    for (int o = 0; o < CH; ++o) {
        const float* wo = &sw[o * CH * 3];
        #pragma unroll
        for (int j = 0; j < 2; ++j) {
            int wx = tid + j * 256;
            float acc = sb[o];
            #pragma unroll
            for (int i = 0; i < CH; ++i)
                acc += sp[i][wx] * wo[i*3+0] + sp[i][wx+1] * wo[i*3+1] + sp[i][wx+2] * wo[i*3+2];
            O[(((size_t)b * CH + o) * NBINS + h) * WW + wx] = acc;
        }
    }
}

// ---------------------------------------------------------------- rotary -> QR bf16 (w,d) + VT bf16 (d,w)
__global__ __launch_bounds__(256)
void rotary_qv(const float* __restrict__ PC, u16* __restrict__ QR,
               u16* __restrict__ VT, int bcn_base)
{
    int bcnl = blockIdx.x >> 4, wt = blockIdx.x & 15;
    int bcn = bcn_base + bcnl;
    int bc = bcn >> 2, n = bcn & 3;
    int w0 = wt * 32;
    __shared__ float tl[32][256 + 1];
    int tid = threadIdx.x;
    const float* src = PC + ((size_t)bc * NBINS + n * 256) * WW + w0;
    int wi = tid & 31, dbase = tid >> 5;
    for (int rep = 0; rep < 32; ++rep) {
        int d = dbase * 32 + rep;
        float v = src[(size_t)d * WW + wi];
        tl[wi][d] = v;
        VT[((size_t)bcnl * 256 + d) * 512 + w0 + wi] = bfr(v);
    }
    __syncthreads();
    int dp = tid & 127;
    int wg = tid >> 7;
    bool rot = dp < 64;
    float freq = 0.f;
    if (rot) freq = exp2f(-0.20762050593048203f * (float)dp); // 10000^(-dp/64)
    for (int j = 0; j < 16; ++j) {
        int wl = wg * 16 + j;
        float t1 = tl[wl][2 * dp], t2 = tl[wl][2 * dp + 1];
        float o1, o2;
        if (rot) {
            float ang = (float)(w0 + wl) * freq;
            float sn, cn;
            sincosf(ang, &sn, &cn);
            o1 = t1 * cn - t2 * sn;
            o2 = t2 * cn + t1 * sn;
        } else { o1 = t1; o2 = t2; }
        ushort2 pk; pk.x = bfr(o1); pk.y = bfr(o2);
        *(ushort2*)&QR[((size_t)bcnl * 512 + w0 + wl) * 256 + 2 * dp] = pk;
    }
}

// ---------------------------------------------------------------- softmax fp32 rows -> bf16 P
__global__ __launch_bounds__(256)
void softmax_bf(const float* __restrict__ S, u16* __restrict__ P, int nrows)
{
    int gid = blockIdx.x * 256 + threadIdx.x;
    int row = gid >> 6, lane = threadIdx.x & 63;
    if (row >= nrows) return;
    const float* r = S + (size_t)row * 512;
    float4 a = ((const float4*)r)[lane];
    float4 b = ((const float4*)r)[lane + 64];
    float mx = fmaxf(fmaxf(fmaxf(a.x, a.y), fmaxf(a.z, a.w)),
                     fmaxf(fmaxf(b.x, b.y), fmaxf(b.z, b.w)));
    for (int off = 32; off; off >>= 1) mx = fmaxf(mx, __shfl_xor(mx, off));
    a.x = __expf(a.x - mx); a.y = __expf(a.y - mx); a.z = __expf(a.z - mx); a.w = __expf(a.w - mx);
    b.x = __expf(b.x - mx); b.y = __expf(b.y - mx); b.z = __expf(b.z - mx); b.w = __expf(b.w - mx);
    float sm = a.x + a.y + a.z + a.w + b.x + b.y + b.z + b.w;
    for (int off = 32; off; off >>= 1) sm += __shfl_xor(sm, off);
    float inv = 1.f / sm;
    u16* pr = P + (size_t)row * 512;
    ushort4 pa, pb;
    pa.x = bfr(a.x*inv); pa.y = bfr(a.y*inv); pa.z = bfr(a.z*inv); pa.w = bfr(a.w*inv);
    pb.x = bfr(b.x*inv); pb.y = bfr(b.y*inv); pb.z = bfr(b.z*inv); pb.w = bfr(b.w*inv);
    *(ushort4*)&pr[4 * lane]       = pa;
    *(ushort4*)&pr[256 + 4 * lane] = pb;
}

// ---------------------------------------------------------------- residual add
__global__ __launch_bounds__(256)
void add_k(const float* __restrict__ A, const float* B, float* O, int n4)
{
    int i = blockIdx.x * 256 + threadIdx.x;
    if (i >= n4) return;
    float4 a = ((const float4*)A)[i];
    float4 b = ((const float4*)B)[i];
    ((float4*)O)[i] = make_float4(a.x + b.x, a.y + b.y, a.z + b.z, a.w + b.w);
}

// ---------------------------------------------------------------- bf16 MFMA GEMM (NT)
// C[m,n] = sum_k A[m,k]*B[n,k], A (M,K) B (N,K) bf16 row-major.
// BM=128 x BN (64|128), BK=64, 4 waves (2x2), global_load_lds + XOR swizzle,
// XCD-chunked bijective block swizzle for L2 A-panel reuse.
// MODE 0: C fp32 = acc*scale; 1: C bf16 = acc; 2: CT bf16 = relu(acc)^2 (ldC=M);
// MODE 3: C fp32 += acc.
template<int MODE, int BN>
__global__ __launch_bounds__(256)
void gemm_bt(const u16* __restrict__ A, const u16* __restrict__ B,
             void* __restrict__ Cvoid,
             int K, int tilesN, int tilesPerBatch,
             size_t aStride, size_t bStride,
             int aAdd, int aMod,
             int cDiv, size_t cMul1, size_t cMul2, size_t cAdd2,
             int ldC, float scale)
{
    // XCD-chunked bijective swizzle (8 XCDs): contiguous block ranges per XCD.
    int swz;
    {
        const int nwg = gridDim.x;
        const int q = nwg >> 3, r = nwg & 7;
        const int xcd = blockIdx.x & 7, idx = blockIdx.x >> 3;
        swz = (xcd < r ? xcd * (q + 1) : r * (q + 1) + (xcd - r) * q) + idx;
    }
    const int batch = swz / tilesPerBatch;
    const int t  = swz % tilesPerBatch;
    const int tm = t / tilesN, tn = t % tilesN;
    const int aIdx = (batch + aAdd) % aMod;
    const size_t cOff = cMul1 * (size_t)(batch / cDiv) + cMul2 * (size_t)(batch % cDiv) + cAdd2;

    const u16* Ab = A + (size_t)aIdx * aStride + (size_t)(tm * 128) * K;
    const u16* Bb = B + (size_t)batch * bStride + (size_t)(tn * BN) * K;

    __shared__ u16 As[128 * 64];
    __shared__ u16 Bs[BN * 64];

    const int tid = threadIdx.x;
    const int wv = tid >> 6, l = tid & 63;
    const int wm = wv >> 1, wn = wv & 1;
    const int lr = l & 15, lk = l >> 4;
    constexpr int NI = BN / 32;      // 16-col fragments per wave in N

    f32x4 acc[4][NI];
    #pragma unroll
    for (int i = 0; i < 4; ++i)
        #pragma unroll
        for (int j = 0; j < NI; ++j)
            acc[i][j] = (f32x4){0.f, 0.f, 0.f, 0.f};

    for (int k0 = 0; k0 < K; k0 += 64) {
        __syncthreads();            // prior reads done before LDS overwrite
        #pragma unroll
        for (int it = 0; it < 4; ++it) {            // A: 128 rows
            int chunk = (it * 4 + wv) * 64 + l;     // 16B chunks
            int row = chunk >> 3, cb = chunk & 7;
            int cbg = cb ^ (row & 7);               // inverse-swizzled source
            const char* sa = (const char*)Ab + ((size_t)row * K + k0 + cbg * 8) * 2;
            char* da = (char*)As + (it * 4 + wv) * 1024;
            __builtin_amdgcn_global_load_lds((const __attribute__((address_space(1))) void*)sa,
                                             (__attribute__((address_space(3))) void*)da, 16, 0, 0);
        }
        #pragma unroll
        for (int it = 0; it < BN / 32; ++it) {      // B: BN rows
            int chunk = (it * 4 + wv) * 64 + l;
            int row = chunk >> 3, cb = chunk & 7;
            int cbg = cb ^ (row & 7);
            const char* sb = (const char*)Bb + ((size_t)row * K + k0 + cbg * 8) * 2;
            char* db = (char*)Bs + (it * 4 + wv) * 1024;
            __builtin_amdgcn_global_load_lds((const __attribute__((address_space(1))) void*)sb,
                                             (__attribute__((address_space(3))) void*)db, 16, 0, 0);
        }
        __syncthreads();            // implies vmcnt(0): staging visible
        #pragma unroll
        for (int kk = 0; kk < 2; ++kk) {
            bf16x8 av[4], bv[NI];
            #pragma unroll
            for (int mi = 0; mi < 4; ++mi) {
                int row = wm * 64 + mi * 16 + lr;
                int off = row * 128 + (((kk << 6) | (lk << 4)) ^ ((row & 7) << 4));
                av[mi] = *(const bf16x8*)((const char*)As + off);
            }
            #pragma unroll
            for (int ni = 0; ni < NI; ++ni) {
                int row = wn * (BN / 2) + ni * 16 + lr;
                int off = row * 128 + (((kk << 6) | (lk << 4)) ^ ((row & 7) << 4));
                bv[ni] = *(const bf16x8*)((const char*)Bs + off);
            }
            #pragma unroll
            for (int mi = 0; mi < 4; ++mi)
                #pragma unroll
                for (int ni = 0; ni < NI; ++ni)
                    acc[mi][ni] = __builtin_amdgcn_mfma_f32_16x16x32_bf16(
                        av[mi], bv[ni], acc[mi][ni], 0, 0, 0);
        }
    }

    const int rowBase = tm * 128 + wm * 64;
    const int colBase = tn * BN + wn * (BN / 2);
    if (MODE == 0) {
        float* Cf = (float*)Cvoid;
        #pragma unroll
        for (int mi = 0; mi < 4; ++mi)
            #pragma unroll
            for (int ni = 0; ni < NI; ++ni) {
                int r0 = rowBase + mi * 16 + lk * 4;
                int c  = colBase + ni * 16 + lr;
                #pragma unroll
                for (int r = 0; r < 4; ++r)
                    Cf[cOff + (size_t)(r0 + r) * ldC + c] = acc[mi][ni][r] * scale;
            }
    } else if (MODE == 1) {
        u16* Cb = (u16*)Cvoid;
        #pragma unroll
        for (int mi = 0; mi < 4; ++mi)
            #pragma unroll
            for (int ni = 0; ni < NI; ++ni) {
                int r0 = rowBase + mi * 16 + lk * 4;
                int c  = colBase + ni * 16 + lr;
                #pragma unroll
                for (int r = 0; r < 4; ++r)
                    Cb[cOff + (size_t)(r0 + r) * ldC + c] = bfr(acc[mi][ni][r]);
            }
    } else if (MODE == 2) {
        u16* Cb = (u16*)Cvoid;
        #pragma unroll
        for (int mi = 0; mi < 4; ++mi)
            #pragma unroll
            for (int ni = 0; ni < NI; ++ni) {
                int r0 = rowBase + mi * 16 + lk * 4;
                int c  = colBase + ni * 16 + lr;
                ushort4 pk;
                float v0 = fmaxf(acc[mi][ni][0], 0.f);
                float v1 = fmaxf(acc[mi][ni][1], 0.f);
                float v2 = fmaxf(acc[mi][ni][2], 0.f);
                float v3 = fmaxf(acc[mi][ni][3], 0.f);
                pk.x = bfr(v0 * v0); pk.y = bfr(v1 * v1);
                pk.z = bfr(v2 * v2); pk.w = bfr(v3 * v3);
                *(ushort4*)&Cb[cOff + (size_t)c * ldC + r0] = pk;
            }
    } else {
        float* Cf = (float*)Cvoid;
        #pragma unroll
        for (int mi = 0; mi < 4; ++mi)
            #pragma unroll
            for (int ni = 0; ni < NI; ++ni) {
                int r0 = rowBase + mi * 16 + lk * 4;
                int c  = colBase + ni * 16 + lr;
                #pragma unroll
                for (int r = 0; r < 4; ++r)
                    Cf[cOff + (size_t)(r0 + r) * ldC + c] += acc[mi][ni][r];
            }
    }
}

// ---------------------------------------------------------------- launcher
extern "C" void kernel_launch(void* const* d_in, const int* in_sizes, int n_in,
                              void* d_out, int out_size, void* d_ws, size_t ws_size,
                              hipStream_t stream)
{
    const float* x        = (const float*)d_in[0];
    const float* ln1_w    = (const float*)d_in[1];
    const float* ln1_b    = (const float*)d_in[2];
    const float* q_mcl_w  = (const float*)d_in[3];
    const float* q_conv_w = (const float*)d_in[4];
    const float* q_conv_b = (const float*)d_in[5];
    const float* out_mcl_w= (const float*)d_in[6];
    const float* ln2_w    = (const float*)d_in[7];
    const float* ln2_b    = (const float*)d_in[8];
    const float* lin1_w   = (const float*)d_in[9];
    const float* lin2_w   = (const float*)d_in[10];
    float* OUT = (float*)d_out;
    char*  WB  = (char*)d_ws;

    int ga = 4;
    {   const int cands[4] = {32, 16, 8, 4};
        for (int i = 0; i < 4; ++i)
            if (16777216ull + (size_t)cands[i] * 2359296ull <= ws_size) { ga = cands[i]; break; }
    }
    int mc = 1;
    {   const int cands[3] = {4, 2, 1};
        for (int i = 0; i < 3; ++i)
            if ((size_t)cands[i] * 18874368ull <= ws_size) { mc = cands[i]; break; }
    }

    // ---- Phase A: norm1 + q_mcl + conv
    u16* QW  = (u16*)WB;                    // 16.8MB
    u16* Z1T = (u16*)(WB + 16777216);       // 16.8MB
    cvt_k<<<8192, 256, 0, stream>>>(q_mcl_w, QW, 2097152);
    frame_norm_t<<<256, 256, 0, stream>>>(x, ln1_w, ln1_b, Z1T, 0, 1, 0);
    gemm_bt<0, 64><<<1024, 256, 0, stream>>>(QW, Z1T, OUT, 1024, 8, 64,
        1048576, 524288, 0, 8, 1, PLANE, 0, 0, 512, 1.f);
    conv1x3_k<<<2048, 256, 0, stream>>>(OUT, q_conv_w, q_conv_b, OUT);

    // ---- Phase B: attention, groups of ga bcn
    u16* OW = (u16*)WB;                                         // 16.8MB (reuse QW)
    char* pb = WB + 16777216;
    u16*   QR = (u16*)pb;                                       // ga*256KB
    u16*   VT = (u16*)(pb + (size_t)ga * 262144);               // ga*256KB
    float* S  = (float*)(pb + (size_t)ga * 524288);             // ga*1MB
    u16*   P  = (u16*)(pb + (size_t)ga * 1572864);              // ga*512KB
    u16*   A2 = (u16*)(pb + (size_t)ga * 2097152);              // (ga/4)*1MB
    cvt_k<<<8192, 256, 0, stream>>>(out_mcl_w, OW, 2097152);
    {
        const int nG = 64 / ga;
        for (int g = 0; g < nG; ++g) {
            const int bcn0 = g * ga, bc0 = bcn0 / 4;
            rotary_qv<<<ga * 16, 256, 0, stream>>>(OUT, QR, VT, bcn0);
            // scores: M=512,N=512,K=256 -> BN=64: tilesN=8, tpb=32
            gemm_bt<0, 64><<<ga * 32, 256, 0, stream>>>(QR, QR, S, 256, 8, 32,
                131072, 131072, 0, 1000000, 1, 262144, 0, 0, 512, 0.03125f);
            softmax_bf<<<ga * 128, 256, 0, stream>>>(S, P, ga * 512);
            // PV: M=512,N=256,K=512 -> BN=64: tilesN=4, tpb=16
            gemm_bt<1, 64><<<ga * 16, 256, 0, stream>>>(P, VT, A2, 512, 4, 16,
                262144, 131072, 0, 1000000, 4, 524288, 256, 0, 1024, 1.f);
            // out_mcl: M=1024,N=512,K=1024 -> BN=64: tilesN=8, tpb=64
            gemm_bt<0, 64><<<(ga / 4) * 64, 256, 0, stream>>>(OW, A2, OUT, 1024, 8, 64,
                1048576, 524288, bc0, 8, 1, PLANE, 0, (size_t)bc0 * PLANE, 512, 1.f);
        }
    }

    // ---- residual
    add_k<<<8192, 256, 0, stream>>>(x, OUT, OUT, (int)(TENS / 4));

    // ---- Phase C: MLP, groups of mc channels (both batches => 2mc local)
    u16* WC  = (u16*)WB;                                        // mc*8.4MB
    u16* Z2T = (u16*)(WB + (size_t)mc * 8388608);               // 2mc*1MB
    u16* HT  = (u16*)(WB + (size_t)mc * 8388608 + (size_t)mc * 2097152); // 2mc*4.2MB
    {
        const int nG = 8 / mc;
        for (int g = 0; g < nG; ++g) {
            const int cBase = g * mc;
            cvt_k<<<mc * 4096, 256, 0, stream>>>(lin1_w + (size_t)cBase * 4194304, WC, mc * 1048576);
            frame_norm_t<<<2 * mc * 16, 256, 0, stream>>>(OUT, ln2_w, ln2_b, Z2T, 1, mc, cBase);
            // lin1: M=4096,N=512,K=1024, BN=128: tilesN=4, tpb=128
            gemm_bt<2, 128><<<2 * mc * 128, 256, 0, stream>>>(WC, Z2T, HT, 1024, 4, 128,
                4194304, 524288, 0, mc, 1, 2097152, 0, 0, 4096, 1.f);
            cvt_k<<<mc * 4096, 256, 0, stream>>>(lin2_w + (size_t)cBase * 4194304, WC, mc * 1048576);
            // lin2: M=1024,N=512,K=4096, BN=64: tilesN=8, tpb=64
            gemm_bt<3, 64><<<2 * mc * 64, 256, 0, stream>>>(WC, HT, OUT, 4096, 8, 64,
                4194304, 2097152, 0, mc, mc, 8 * PLANE, PLANE, (size_t)cBase * PLANE, 512, 1.f);
        }
    }
}

// Round 5
// 582.232 us; speedup vs baseline: 4.5198x; 1.1323x over previous
//
#include <hip/hip_runtime.h>
#include <math.h>

typedef unsigned short u16;
#define CH    8
#define NBINS 1024
#define WW    512

static const size_t PLANE = (size_t)NBINS * WW;   // 524288
static const size_t TENS  = 16 * PLANE;           // 8388608

using bf16x8 = __attribute__((ext_vector_type(8))) short;
using f32x4  = __attribute__((ext_vector_type(4))) float;

__device__ __forceinline__ u16 bfr(float f) {
    union { float f; unsigned u; } x; x.f = f;
    return (u16)((x.u + 0x7FFFu + ((x.u >> 16) & 1u)) >> 16);
}

// ---------------------------------------------------------------- fp32 -> bf16
__global__ __launch_bounds__(256)
void cvt_k(const float* __restrict__ src, u16* __restrict__ dst, int n4)
{
    int i = blockIdx.x * 256 + threadIdx.x;
    if (i >= n4) return;
    float4 f = ((const float4*)src)[i];
    ushort4 o;
    o.x = bfr(f.x); o.y = bfr(f.y); o.z = bfr(f.z); o.w = bfr(f.w);
    ((ushort4*)dst)[i] = o;
}

// ---------------------------------------------------------------- frame norm -> transposed bf16
__global__ __launch_bounds__(256)
void frame_norm_t(const float* __restrict__ X, const float* __restrict__ gw,
                  const float* __restrict__ gb, u16* __restrict__ O,
                  int useMap, int mc, int cBase)
{
    int lb = blockIdx.x >> 4, wt = blockIdx.x & 15;
    int bc = useMap ? ((lb / mc) * 8 + cBase + (lb % mc)) : lb;
    const float* xb = X + (size_t)bc * PLANE + wt * 32;
    int wi = threadIdx.x & 31, hg = threadIdx.x >> 5;

    float s = 0.f, s2 = 0.f;
    for (int h = hg * 128; h < hg * 128 + 128; ++h) {
        float v = xb[(size_t)h * WW + wi];
        s += v; s2 += v * v;
    }
    __shared__ float sh[2][8][32];
    __shared__ float smean[32], srstd[32];
    sh[0][hg][wi] = s; sh[1][hg][wi] = s2;
    __syncthreads();
    if (threadIdx.x < 32) {
        float ts = 0.f, ts2 = 0.f;
        for (int g = 0; g < 8; ++g) { ts += sh[0][g][threadIdx.x]; ts2 += sh[1][g][threadIdx.x]; }
        float mean = ts * (1.f / 1024.f);
        float var  = ts2 * (1.f / 1024.f) - mean * mean;
        smean[threadIdx.x] = mean;
        srstd[threadIdx.x] = rsqrtf(var + 1e-5f);
    }
    __syncthreads();
    float mean = smean[wi], rstd = srstd[wi];
    u16* ob = O + ((size_t)lb * 512 + wt * 32 + wi) * 1024;
    for (int h0 = hg * 128; h0 < hg * 128 + 128; h0 += 4) {
        ushort4 pk;
        float v0 = xb[(size_t)(h0+0) * WW + wi];
        float v1 = xb[(size_t)(h0+1) * WW + wi];
        float v2 = xb[(size_t)(h0+2) * WW + wi];
        float v3 = xb[(size_t)(h0+3) * WW + wi];
        pk.x = bfr((v0 - mean) * rstd * gw[h0+0] + gb[h0+0]);
        pk.y = bfr((v1 - mean) * rstd * gw[h0+1] + gb[h0+1]);
        pk.z = bfr((v2 - mean) * rstd * gw[h0+2] + gb[h0+2]);
        pk.w = bfr((v3 - mean) * rstd * gw[h0+3] + gb[h0+3]);
        *(ushort4*)&ob[h0] = pk;
    }
}

// ---------------------------------------------------------------- conv 1x3 (fp32, in-place safe)
__global__ __launch_bounds__(256)
void conv1x3_k(const float* __restrict__ P, const float* __restrict__ Wc,
               const float* __restrict__ Bc, float* __restrict__ O)
{
    int b = blockIdx.x >> 10, h = blockIdx.x & 1023;
    __shared__ float sp[CH][WW + 2];
    __shared__ float sw[CH * CH * 3];
    __shared__ float sb[CH];
    int tid = threadIdx.x;
    #pragma unroll
    for (int i = 0; i < CH; ++i) {
        size_t base = (((size_t)b * CH + i) * NBINS + h) * WW;
        sp[i][1 + tid]       = P[base + tid];
        sp[i][1 + 256 + tid] = P[base + 256 + tid];
    }
    if (tid < CH) { sp[tid][0] = 0.f; sp[tid][WW + 1] = 0.f; sb[tid] = Bc[tid]; }
    if (tid < CH * CH * 3) sw[tid] = Wc[tid];
    __syncthreads();
    #pragma unroll
    for (int o = 0; o < CH; ++o) {
        const float* wo = &sw[o * CH * 3];
        #pragma unroll
        for (int j = 0; j < 2; ++j) {
            int wx = tid + j * 256;
            float acc = sb[o];
            #pragma unroll
            for (int i = 0; i < CH; ++i)
                acc += sp[i][wx] * wo[i*3+0] + sp[i][wx+1] * wo[i*3+1] + sp[i][wx+2] * wo[i*3+2];
            O[(((size_t)b * CH + o) * NBINS + h) * WW + wx] = acc;
        }
    }
}

// ---------------------------------------------------------------- rotary -> QR bf16 (w,d) + VT bf16 (d,w)
__global__ __launch_bounds__(256)
void rotary_qv(const float* __restrict__ PC, u16* __restrict__ QR,
               u16* __restrict__ VT, int bcn_base)
{
    int bcnl = blockIdx.x >> 4, wt = blockIdx.x & 15;
    int bcn = bcn_base + bcnl;
    int bc = bcn >> 2, n = bcn & 3;
    int w0 = wt * 32;
    __shared__ float tl[32][256 + 1];
    int tid = threadIdx.x;
    const float* src = PC + ((size_t)bc * NBINS + n * 256) * WW + w0;
    int wi = tid & 31, dbase = tid >> 5;
    for (int rep = 0; rep < 32; ++rep) {
        int d = dbase * 32 + rep;
        float v = src[(size_t)d * WW + wi];
        tl[wi][d] = v;
        VT[((size_t)bcnl * 256 + d) * 512 + w0 + wi] = bfr(v);
    }
    __syncthreads();
    int dp = tid & 127;
    int wg = tid >> 7;
    bool rot = dp < 64;
    float freq = 0.f;
    if (rot) freq = exp2f(-0.20762050593048203f * (float)dp); // 10000^(-dp/64)
    for (int j = 0; j < 16; ++j) {
        int wl = wg * 16 + j;
        float t1 = tl[wl][2 * dp], t2 = tl[wl][2 * dp + 1];
        float o1, o2;
        if (rot) {
            float ang = (float)(w0 + wl) * freq;
            float sn, cn;
            sincosf(ang, &sn, &cn);
            o1 = t1 * cn - t2 * sn;
            o2 = t2 * cn + t1 * sn;
        } else { o1 = t1; o2 = t2; }
        ushort2 pk; pk.x = bfr(o1); pk.y = bfr(o2);
        *(ushort2*)&QR[((size_t)bcnl * 512 + w0 + wl) * 256 + 2 * dp] = pk;
    }
}

// ---------------------------------------------------------------- fused flash attention
// One block = (bcnl, q-tile of 64 rows); 4 waves x 16 q-rows.
// QR (bcnl, w, d) bf16; VT (bcnl, d, w) bf16. Output A2 (bc_local, w, h) bf16.
// Online softmax, scale 1/32. KV tiles of 64 staged in swizzled LDS.
__global__ __launch_bounds__(256)
void flash_attn(const u16* __restrict__ QR, const u16* __restrict__ VT,
                u16* __restrict__ A2)
{
    const int blk = blockIdx.x;
    const int bcnl = blk >> 3, qt = blk & 7;
    const int nh = bcnl & 3;                 // head index (ga multiple of 4)

    __shared__ u16 Ks[64 * 256];             // rows k (512B each), swizzled
    __shared__ u16 Vs[256 * 64];             // rows d (128B each), swizzled
    __shared__ u16 Ps[4][16 * 72];           // per-wave P (16 q x 64 k, pad 72)

    const int tid = threadIdx.x;
    const int wv = tid >> 6, l = tid & 63;
    const int lr = l & 15, lk = l >> 4;
    const int q0w = qt * 64 + wv * 16;

    const char* QRb = (const char*)(QR + (size_t)bcnl * 131072);
    const char* VTb = (const char*)(VT + (size_t)bcnl * 131072);

    // Q fragments: row = q0w + lr, d-chunk dk (32 elems), this lane's 8 at lk*8
    bf16x8 qf[8];
    #pragma unroll
    for (int dk = 0; dk < 8; ++dk)
        qf[dk] = *(const bf16x8*)(QRb + ((size_t)(q0w + lr) * 512 + dk * 64 + lk * 16));

    f32x4 acc[16];
    #pragma unroll
    for (int i = 0; i < 16; ++i) acc[i] = (f32x4){0.f, 0.f, 0.f, 0.f};
    float m_r[4] = {-1e30f, -1e30f, -1e30f, -1e30f};
    float l_r[4] = {0.f, 0.f, 0.f, 0.f};

    for (int kt = 0; kt < 8; ++kt) {
        __syncthreads();                     // prior tile's LDS reads done
        // stage K tile: 64 rows x 32 chunks of 16B
        #pragma unroll
        for (int it = 0; it < 8; ++it) {
            int chunk = it * 256 + tid;
            int row = chunk >> 5, cb = chunk & 31;
            int cbg = cb ^ (row & 7);
            const char* s = QRb + ((size_t)(kt * 64 + row) * 512 + cbg * 16);
            char* d = (char*)Ks + (size_t)chunk * 16;
            __builtin_amdgcn_global_load_lds((const __attribute__((address_space(1))) void*)s,
                                             (__attribute__((address_space(3))) void*)d, 16, 0, 0);
        }
        // stage V tile: 256 rows x 8 chunks of 16B
        #pragma unroll
        for (int it = 0; it < 8; ++it) {
            int chunk = it * 256 + tid;
            int row = chunk >> 3, cb = chunk & 7;
            int cbg = cb ^ (row & 7);
            const char* s = VTb + ((size_t)row * 1024 + kt * 128 + cbg * 16);
            char* d = (char*)Vs + (size_t)chunk * 16;
            __builtin_amdgcn_global_load_lds((const __attribute__((address_space(1))) void*)s,
                                             (__attribute__((address_space(3))) void*)d, 16, 0, 0);
        }
        __syncthreads();                     // staging visible (drains vmcnt)

        // QK^T: S[16 q][64 k]
        f32x4 s4[4];
        #pragma unroll
        for (int n = 0; n < 4; ++n) s4[n] = (f32x4){0.f, 0.f, 0.f, 0.f};
        #pragma unroll
        for (int dk = 0; dk < 8; ++dk) {
            #pragma unroll
            for (int n = 0; n < 4; ++n) {
                int row = n * 16 + lr;
                int off = row * 512 + ((dk * 64 + lk * 16) ^ ((row & 7) << 4));
                bf16x8 kv = *(const bf16x8*)((const char*)Ks + off);
                s4[n] = __builtin_amdgcn_mfma_f32_16x16x32_bf16(qf[dk], kv, s4[n], 0, 0, 0);
            }
        }

        // online softmax (rows r; state replicated across 16-lane groups)
        float alpha[4];
        #pragma unroll
        for (int r = 0; r < 4; ++r) {
            float v = fmaxf(fmaxf(s4[0][r], s4[1][r]), fmaxf(s4[2][r], s4[3][r]));
            v = fmaxf(v, __shfl_xor(v, 1));
            v = fmaxf(v, __shfl_xor(v, 2));
            v = fmaxf(v, __shfl_xor(v, 4));
            v = fmaxf(v, __shfl_xor(v, 8));
            float mn = fmaxf(m_r[r], v * 0.03125f);
            alpha[r] = __expf(m_r[r] - mn);
            m_r[r] = mn;
        }
        float psum[4] = {0.f, 0.f, 0.f, 0.f};
        #pragma unroll
        for (int n = 0; n < 4; ++n)
            #pragma unroll
            for (int r = 0; r < 4; ++r) {
                float p = __expf(s4[n][r] * 0.03125f - m_r[r]);
                psum[r] += p;
                Ps[wv][(lk * 4 + r) * 72 + n * 16 + lr] = bfr(p);
            }
        #pragma unroll
        for (int r = 0; r < 4; ++r) {
            float v = psum[r];
            v += __shfl_xor(v, 1); v += __shfl_xor(v, 2);
            v += __shfl_xor(v, 4); v += __shfl_xor(v, 8);
            l_r[r] = l_r[r] * alpha[r] + v;
        }
        // rescale O
        #pragma unroll
        for (int df = 0; df < 16; ++df)
            #pragma unroll
            for (int r = 0; r < 4; ++r)
                acc[df][r] *= alpha[r];

        // PV: A = P (16 q x 64 k), B = V rows d
        bf16x8 pf[2];
        #pragma unroll
        for (int k2 = 0; k2 < 2; ++k2)
            pf[k2] = *(const bf16x8*)((const char*)&Ps[wv][0] + lr * 144 + k2 * 64 + lk * 16);
        #pragma unroll
        for (int df = 0; df < 16; ++df) {
            #pragma unroll
            for (int k2 = 0; k2 < 2; ++k2) {
                int row = df * 16 + lr;
                int off = row * 128 + ((k2 * 64 + lk * 16) ^ ((row & 7) << 4));
                bf16x8 vv = *(const bf16x8*)((const char*)Vs + off);
                acc[df] = __builtin_amdgcn_mfma_f32_16x16x32_bf16(pf[k2], vv, acc[df], 0, 0, 0);
            }
        }
    }

    // epilogue: O /= l, write A2[(bcnl>>2)][q][nh*256 + d]
    float invl[4];
    #pragma unroll
    for (int r = 0; r < 4; ++r) invl[r] = 1.f / l_r[r];
    u16* A2b = A2 + (size_t)(bcnl >> 2) * 524288 + (size_t)nh * 256;
    #pragma unroll
    for (int df = 0; df < 16; ++df)
        #pragma unroll
        for (int r = 0; r < 4; ++r) {
            int q = q0w + lk * 4 + r;
            int d = df * 16 + lr;
            A2b[(size_t)q * 1024 + d] = bfr(acc[df][r] * invl[r]);
        }
}

// ---------------------------------------------------------------- bf16 MFMA GEMM (NT)
// C[m,n] = sum_k A[m,k]*B[n,k], A (M,K) B (N,K) bf16 row-major.
// BM=128 x BN (64|128), BK=64, 4 waves (2x2), global_load_lds + XOR swizzle,
// XCD-chunked bijective block swizzle.
// MODE 0: C fp32 = acc*scale; 2: CT bf16 = relu(acc)^2 (ldC=M);
// MODE 3: C fp32 += acc; 4: C fp32 = Xres + acc  (fused residual).
template<int MODE, int BN>
__global__ __launch_bounds__(256)
void gemm_bt(const u16* __restrict__ A, const u16* __restrict__ B,
             void* __restrict__ Cvoid,
             int K, int tilesN, int tilesPerBatch,
             size_t aStride, size_t bStride,
             int aAdd, int aMod,
             int cDiv, size_t cMul1, size_t cMul2, size_t cAdd2,
             int ldC, float scale, const float* __restrict__ Xres)
{
    int swz;
    {
        const int nwg = gridDim.x;
        const int q = nwg >> 3, r = nwg & 7;
        const int xcd = blockIdx.x & 7, idx = blockIdx.x >> 3;
        swz = (xcd < r ? xcd * (q + 1) : r * (q + 1) + (xcd - r) * q) + idx;
    }
    const int batch = swz / tilesPerBatch;
    const int t  = swz % tilesPerBatch;
    const int tm = t / tilesN, tn = t % tilesN;
    const int aIdx = (batch + aAdd) % aMod;
    const size_t cOff = cMul1 * (size_t)(batch / cDiv) + cMul2 * (size_t)(batch % cDiv) + cAdd2;

    const u16* Ab = A + (size_t)aIdx * aStride + (size_t)(tm * 128) * K;
    const u16* Bb = B + (size_t)batch * bStride + (size_t)(tn * BN) * K;

    __shared__ u16 As[128 * 64];
    __shared__ u16 Bs[BN * 64];

    const int tid = threadIdx.x;
    const int wv = tid >> 6, l = tid & 63;
    const int wm = wv >> 1, wn = wv & 1;
    const int lr = l & 15, lk = l >> 4;
    constexpr int NI = BN / 32;

    f32x4 acc[4][NI];
    #pragma unroll
    for (int i = 0; i < 4; ++i)
        #pragma unroll
        for (int j = 0; j < NI; ++j)
            acc[i][j] = (f32x4){0.f, 0.f, 0.f, 0.f};

    for (int k0 = 0; k0 < K; k0 += 64) {
        __syncthreads();
        #pragma unroll
        for (int it = 0; it < 4; ++it) {
            int chunk = (it * 4 + wv) * 64 + l;
            int row = chunk >> 3, cb = chunk & 7;
            int cbg = cb ^ (row & 7);
            const char* sa = (const char*)Ab + ((size_t)row * K + k0 + cbg * 8) * 2;
            char* da = (char*)As + (it * 4 + wv) * 1024;
            __builtin_amdgcn_global_load_lds((const __attribute__((address_space(1))) void*)sa,
                                             (__attribute__((address_space(3))) void*)da, 16, 0, 0);
        }
        #pragma unroll
        for (int it = 0; it < BN / 32; ++it) {
            int chunk = (it * 4 + wv) * 64 + l;
            int row = chunk >> 3, cb = chunk & 7;
            int cbg = cb ^ (row & 7);
            const char* sb = (const char*)Bb + ((size_t)row * K + k0 + cbg * 8) * 2;
            char* db = (char*)Bs + (it * 4 + wv) * 1024;
            __builtin_amdgcn_global_load_lds((const __attribute__((address_space(1))) void*)sb,
                                             (__attribute__((address_space(3))) void*)db, 16, 0, 0);
        }
        __syncthreads();
        #pragma unroll
        for (int kk = 0; kk < 2; ++kk) {
            bf16x8 av[4], bv[NI];
            #pragma unroll
            for (int mi = 0; mi < 4; ++mi) {
                int row = wm * 64 + mi * 16 + lr;
                int off = row * 128 + (((kk << 6) | (lk << 4)) ^ ((row & 7) << 4));
                av[mi] = *(const bf16x8*)((const char*)As + off);
            }
            #pragma unroll
            for (int ni = 0; ni < NI; ++ni) {
                int row = wn * (BN / 2) + ni * 16 + lr;
                int off = row * 128 + (((kk << 6) | (lk << 4)) ^ ((row & 7) << 4));
                bv[ni] = *(const bf16x8*)((const char*)Bs + off);
            }
            #pragma unroll
            for (int mi = 0; mi < 4; ++mi)
                #pragma unroll
                for (int ni = 0; ni < NI; ++ni)
                    acc[mi][ni] = __builtin_amdgcn_mfma_f32_16x16x32_bf16(
                        av[mi], bv[ni], acc[mi][ni], 0, 0, 0);
        }
    }

    const int rowBase = tm * 128 + wm * 64;
    const int colBase = tn * BN + wn * (BN / 2);
    if (MODE == 0) {
        float* Cf = (float*)Cvoid;
        #pragma unroll
        for (int mi = 0; mi < 4; ++mi)
            #pragma unroll
            for (int ni = 0; ni < NI; ++ni) {
                int r0 = rowBase + mi * 16 + lk * 4;
                int c  = colBase + ni * 16 + lr;
                #pragma unroll
                for (int r = 0; r < 4; ++r)
                    Cf[cOff + (size_t)(r0 + r) * ldC + c] = acc[mi][ni][r] * scale;
            }
    } else if (MODE == 2) {
        u16* Cb = (u16*)Cvoid;
        #pragma unroll
        for (int mi = 0; mi < 4; ++mi)
            #pragma unroll
            for (int ni = 0; ni < NI; ++ni) {
                int r0 = rowBase + mi * 16 + lk * 4;
                int c  = colBase + ni * 16 + lr;
                ushort4 pk;
                float v0 = fmaxf(acc[mi][ni][0], 0.f);
                float v1 = fmaxf(acc[mi][ni][1], 0.f);
                float v2 = fmaxf(acc[mi][ni][2], 0.f);
                float v3 = fmaxf(acc[mi][ni][3], 0.f);
                pk.x = bfr(v0 * v0); pk.y = bfr(v1 * v1);
                pk.z = bfr(v2 * v2); pk.w = bfr(v3 * v3);
                *(ushort4*)&Cb[cOff + (size_t)c * ldC + r0] = pk;
            }
    } else if (MODE == 3) {
        float* Cf = (float*)Cvoid;
        #pragma unroll
        for (int mi = 0; mi < 4; ++mi)
            #pragma unroll
            for (int ni = 0; ni < NI; ++ni) {
                int r0 = rowBase + mi * 16 + lk * 4;
                int c  = colBase + ni * 16 + lr;
                #pragma unroll
                for (int r = 0; r < 4; ++r)
                    Cf[cOff + (size_t)(r0 + r) * ldC + c] += acc[mi][ni][r];
            }
    } else {
        float* Cf = (float*)Cvoid;
        #pragma unroll
        for (int mi = 0; mi < 4; ++mi)
            #pragma unroll
            for (int ni = 0; ni < NI; ++ni) {
                int r0 = rowBase + mi * 16 + lk * 4;
                int c  = colBase + ni * 16 + lr;
                #pragma unroll
                for (int r = 0; r < 4; ++r) {
                    size_t idx = cOff + (size_t)(r0 + r) * ldC + c;
                    Cf[idx] = Xres[idx] + acc[mi][ni][r];
                }
            }
    }
}

// ---------------------------------------------------------------- launcher
extern "C" void kernel_launch(void* const* d_in, const int* in_sizes, int n_in,
                              void* d_out, int out_size, void* d_ws, size_t ws_size,
                              hipStream_t stream)
{
    const float* x        = (const float*)d_in[0];
    const float* ln1_w    = (const float*)d_in[1];
    const float* ln1_b    = (const float*)d_in[2];
    const float* q_mcl_w  = (const float*)d_in[3];
    const float* q_conv_w = (const float*)d_in[4];
    const float* q_conv_b = (const float*)d_in[5];
    const float* out_mcl_w= (const float*)d_in[6];
    const float* ln2_w    = (const float*)d_in[7];
    const float* ln2_b    = (const float*)d_in[8];
    const float* lin1_w   = (const float*)d_in[9];
    const float* lin2_w   = (const float*)d_in[10];
    float* OUT = (float*)d_out;
    char*  WB  = (char*)d_ws;

    // adaptive group sizes
    int ga = 4;
    {   const int cands[5] = {64, 32, 16, 8, 4};
        for (int i = 0; i < 5; ++i)
            if (16777216ull + (size_t)cands[i] * 786432ull <= ws_size) { ga = cands[i]; break; }
    }
    int mc = 1;
    {   const int cands[4] = {8, 4, 2, 1};
        for (int i = 0; i < 4; ++i)
            if ((size_t)cands[i] * 18874368ull <= ws_size) { mc = cands[i]; break; }
    }

    // ---- Phase A: norm1 + q_mcl + conv
    u16* QW  = (u16*)WB;                    // 16.8MB
    u16* Z1T = (u16*)(WB + 16777216);       // 16.8MB
    cvt_k<<<8192, 256, 0, stream>>>(q_mcl_w, QW, 2097152);
    frame_norm_t<<<256, 256, 0, stream>>>(x, ln1_w, ln1_b, Z1T, 0, 1, 0);
    gemm_bt<0, 64><<<1024, 256, 0, stream>>>(QW, Z1T, OUT, 1024, 8, 64,
        1048576, 524288, 0, 8, 1, PLANE, 0, 0, 512, 1.f, nullptr);
    conv1x3_k<<<2048, 256, 0, stream>>>(OUT, q_conv_w, q_conv_b, OUT);

    // ---- Phase B: attention (rotary -> flash -> out_mcl + residual)
    u16* OW = (u16*)WB;                                         // 16.8MB (reuse QW)
    char* pb = WB + 16777216;
    u16* QR = (u16*)pb;                                         // ga*256KB
    u16* VT = (u16*)(pb + (size_t)ga * 262144);                 // ga*256KB
    u16* A2 = (u16*)(pb + (size_t)ga * 524288);                 // ga*256KB
    cvt_k<<<8192, 256, 0, stream>>>(out_mcl_w, OW, 2097152);
    {
        const int nG = 64 / ga;
        for (int g = 0; g < nG; ++g) {
            const int bcn0 = g * ga, bc0 = bcn0 / 4;
            rotary_qv<<<ga * 16, 256, 0, stream>>>(OUT, QR, VT, bcn0);
            flash_attn<<<ga * 8, 256, 0, stream>>>(QR, VT, A2);
            // out_mcl + residual: OUT = x + OW @ A2   (M=1024,N=512,K=1024)
            gemm_bt<4, 64><<<(ga / 4) * 64, 256, 0, stream>>>(OW, A2, OUT, 1024, 8, 64,
                1048576, 524288, bc0, 8, 1, PLANE, 0, (size_t)bc0 * PLANE, 512, 1.f, x);
        }
    }

    // ---- Phase C: MLP, groups of mc channels (both batches => 2mc local)
    u16* WC  = (u16*)WB;                                        // mc*8.4MB
    u16* Z2T = (u16*)(WB + (size_t)mc * 8388608);               // 2mc*1MB
    u16* HT  = (u16*)(WB + (size_t)mc * 8388608 + (size_t)mc * 2097152); // 2mc*4.2MB
    {
        const int nG = 8 / mc;
        for (int g = 0; g < nG; ++g) {
            const int cBase = g * mc;
            cvt_k<<<mc * 4096, 256, 0, stream>>>(lin1_w + (size_t)cBase * 4194304, WC, mc * 1048576);
            frame_norm_t<<<2 * mc * 16, 256, 0, stream>>>(OUT, ln2_w, ln2_b, Z2T, 1, mc, cBase);
            // lin1: M=4096,N=512,K=1024, BN=128
            gemm_bt<2, 128><<<2 * mc * 128, 256, 0, stream>>>(WC, Z2T, HT, 1024, 4, 128,
                4194304, 524288, 0, mc, 1, 2097152, 0, 0, 4096, 1.f, nullptr);
            cvt_k<<<mc * 4096, 256, 0, stream>>>(lin2_w + (size_t)cBase * 4194304, WC, mc * 1048576);
            // lin2: M=1024,N=512,K=4096, BN=64
            gemm_bt<3, 64><<<2 * mc * 64, 256, 0, stream>>>(WC, HT, OUT, 4096, 8, 64,
                4194304, 2097152, 0, mc, mc, 8 * PLANE, PLANE, (size_t)cBase * PLANE, 512, 1.f, nullptr);
        }
    }
}